// Round 19
// baseline (297.428 us; speedup 1.0000x reference)
//
#include <hip/hip_runtime.h>
#include <math.h>
#include <stdint.h>

#define B_    32
#define KOBJ  100
#define NS_   16
#define NK_   8
#define EMB_  1024
#define FEAT_ 2052
#define HID_  1024
#define OUT_  3000
#define COMB_ 512

#define KP1   2112   // FEAT_ padded to 64 (image rows / We1a rows)
#define KP2   2048   // 2*HID_
#define NO_P  3072   // OUT_ padded to 128 (N of o1/o2)
#define KO2   3008   // OUT_ padded to 64 (K of o2)

typedef __attribute__((ext_vector_type(8))) short s16x8;
typedef __attribute__((ext_vector_type(4))) float f32x4;

__device__ inline short f2bf(float f) {
  uint32_t u = __builtin_bit_cast(uint32_t, f);
  u = (u + 0x7fff + ((u >> 16) & 1)) >> 16;  // RNE
  return (short)u;
}
__device__ inline float bf2f(short s) {
  uint32_t u = ((uint32_t)(uint16_t)s) << 16;
  return __builtin_bit_cast(float, u);
}
__device__ inline void gload_lds16(const void* g, void* l) {
  __builtin_amdgcn_global_load_lds(
      (const __attribute__((address_space(1))) void*)g,
      (__attribute__((address_space(3))) void*)l, 16, 0, 0);
}
// XCD-aware bijective remap (m204): consecutive wg cluster on one XCD
__device__ inline int xcd_remap(int fid, int nwg) {
  int q = nwg >> 3, r = nwg & 7;
  int x = fid & 7, l = fid >> 3;
  return (x < r ? x * (q + 1) : r * (q + 1) + (x - r) * q) + l;
}

#define IMG_CHUNKS (B_ * KOBJ * (KP1 / 8))
#define IMG_BLKS   ((IMG_CHUNKS + 255) / 256)
#define Q_CHUNKS   (B_ * (EMB_ / 8))
#define Q_BLKS     ((Q_CHUNKS + 255) / 256)
#define C_BLKS     ((B_ * KOBJ + 255) / 256)

__device__ inline void cvt8_split(const float* __restrict__ in, short* __restrict__ oh,
                                  short* __restrict__ ol, int K, int Kp, int idx) {
  int row = idx / (Kp / 8), c8 = (idx % (Kp / 8)) * 8;
  float f[8];
  if (c8 + 8 <= K) {
    const float* src = in + (size_t)row * K + c8;
    float4 a = *(const float4*)src;
    float4 b = *(const float4*)(src + 4);
    f[0] = a.x; f[1] = a.y; f[2] = a.z; f[3] = a.w;
    f[4] = b.x; f[5] = b.y; f[6] = b.z; f[7] = b.w;
  } else {
#pragma unroll
    for (int i = 0; i < 8; ++i) {
      int k = c8 + i;
      f[i] = (k < K) ? in[(size_t)row * K + k] : 0.f;
    }
  }
  s16x8 vh, vl;
#pragma unroll
  for (int i = 0; i < 8; ++i) {
    short h = f2bf(f[i]);
    vh[i] = h;
    vl[i] = f2bf(f[i] - bf2f(h));
  }
  *(s16x8*)(oh + (size_t)row * Kp + c8) = vh;
  *(s16x8*)(ol + (size_t)row * Kp + c8) = vl;
}

// ---------------- ONE dispatch: all weight transposes + input cvt + centres ----------------
struct TD {
  const float* in; short* oh; short* ol;
  int K, N, Kp, OPM, nkt, split, conv, cum;
};
struct TDs { TD d[8]; };

__global__ __launch_bounds__(256) void prep_all(
    TDs ds, int tcum,
    const float* __restrict__ image, const float* __restrict__ question,
    short* __restrict__ imgb, short* __restrict__ imgl,
    short* __restrict__ qh, short* __restrict__ ql, float* __restrict__ cent) {
  int bid = blockIdx.x, t = threadIdx.x;
  if (bid >= tcum) {
    int bb = bid - tcum;
    if (bb < IMG_BLKS) {
      int idx = bb * 256 + t;
      if (idx < IMG_CHUNKS) cvt8_split(image, imgb, imgl, FEAT_, KP1, idx);
    } else if (bb < IMG_BLKS + Q_BLKS) {
      int idx = (bb - IMG_BLKS) * 256 + t;
      if (idx < Q_CHUNKS) cvt8_split(question, qh, ql, EMB_, EMB_, idx);
    } else {
      int i = (bb - IMG_BLKS - Q_BLKS) * 256 + t;
      if (i < B_ * KOBJ) {
        const float* bbx = image + (size_t)i * FEAT_ + (FEAT_ - 4);
        cent[i * 2 + 0] = 0.5f * (bbx[0] + bbx[2]);
        cent[i * 2 + 1] = 0.5f * (bbx[1] + bbx[3]);
      }
    }
    return;
  }
  __shared__ float s[64][65];
  int i = 0;
  while (i < 7 && bid >= ds.d[i].cum) ++i;
  const TD& d = ds.d[i];
  int local = bid - (i ? ds.d[i - 1].cum : 0);
  int k0 = (local % d.nkt) * 64, n0 = (local / d.nkt) * 64;
  int rr = t >> 4, c4 = (t & 15) * 4;
  bool fullN = d.conv || (n0 + 64 <= d.N);
#pragma unroll
  for (int p = 0; p < 4; ++p) {
    int row = p * 16 + rr;
    int kg = k0 + row;
    float v0 = 0.f, v1 = 0.f, v2 = 0.f, v3 = 0.f;
    if (kg < d.K) {
      const float* src = d.conv
          ? d.in + ((size_t)(n0 / d.OPM) * d.K + kg) * d.OPM + (n0 % d.OPM) + c4
          : d.in + (size_t)kg * d.N + n0 + c4;
      if (fullN) {
        float4 v = *(const float4*)src;
        v0 = v.x; v1 = v.y; v2 = v.z; v3 = v.w;
      } else {
        int nb = n0 + c4;
        if (nb + 0 < d.N) v0 = src[0];
        if (nb + 1 < d.N) v1 = src[1];
        if (nb + 2 < d.N) v2 = src[2];
        if (nb + 3 < d.N) v3 = src[3];
      }
    }
    s[row][c4 + 0] = v0; s[row][c4 + 1] = v1;
    s[row][c4 + 2] = v2; s[row][c4 + 3] = v3;
  }
  __syncthreads();
  int nl = t >> 2, kc = (t & 3) << 4;
#pragma unroll
  for (int half = 0; half < 2; ++half) {
    s16x8 vh, vl;
#pragma unroll
    for (int j = 0; j < 8; ++j) {
      float f = s[kc + half * 8 + j][nl];
      short h = f2bf(f);
      vh[j] = h;
      vl[j] = f2bf(f - bf2f(h));
    }
    size_t o = (size_t)(n0 + nl) * d.Kp + k0 + kc + half * 8;
    *(s16x8*)(d.oh + o) = vh;
    if (d.split) *(s16x8*)(d.ol + o) = vl;
  }
}

// ---------------- MFMA GEMM body (device fn on caller-provided LDS) ----------------
// NOTE: when SPLITK, KS must be a MULTIPLE OF 64 (non-multiple double-counts — R13 bug).
template <int BM, int BN, int WR, int WC, bool SPLIT, bool RELU, bool BIAS, int OMODE,
          bool SPLITK, bool PB16>
__device__ __forceinline__ void gemm_body(
    char* smem, int bx, int by, int bz,
    const short* __restrict__ Ah, const short* __restrict__ Al,
    const short* __restrict__ Bh, const short* __restrict__ Bl,
    const float* __restrict__ bias,
    float* __restrict__ Cf, short* __restrict__ Ch, short* __restrict__ Cl,
    float* __restrict__ part, short* __restrict__ partb, int KS,
    int M, int N, int Kp, int ldc, int Nw) {
  constexpr int NWV = WR * WC;
  constexpr int WM = BM / WR, WN = BN / WC;
  constexpr int FM = WM / 16, FN = WN / 16;
  constexpr int ACH = BM / 8, BCH = BN / 8;
  constexpr int NCH = (ACH + BCH) * (SPLIT ? 2 : 1);
  char* AshC = smem;
  char* BshC = smem + BM * 128;
  char* AslC = smem + (BM + BN) * 128;
  char* BslC = smem + (2 * BM + BN) * 128;
  int tid = threadIdx.x, wave = tid >> 6, lane = tid & 63;
  int wr = wave / WC, wc = wave % WC;
  int r16 = lane & 15, kq = lane >> 4;
  int m0 = by * BM, n0 = bx * BN;
  int kb = SPLITK ? bz * KS : 0;
  int ke = SPLITK ? (kb + KS < Kp ? kb + KS : Kp) : Kp;
  f32x4 acc[FM][FN] = {};

  for (int k0 = kb; k0 < ke; k0 += 64) {
    __syncthreads();
    for (int c = wave; c < NCH; c += NWV) {
      int cc = c;
      const short* g;
      char* l;
      bool isA;
      if (cc < ACH) { isA = true; g = Ah; l = AshC; }
      else if (SPLIT && cc < 2 * ACH) { cc -= ACH; isA = true; g = Al; l = AslC; }
      else {
        cc -= SPLIT ? 2 * ACH : ACH;
        if (cc < BCH) { isA = false; g = Bh; l = BshC; }
        else { cc -= BCH; isA = false; g = Bl; l = BslC; }
      }
      int Lb = cc * 1024 + lane * 16;
      int row = Lb >> 7;
      int off = (Lb & 127) ^ ((row & 7) << 4);
      const short* gsrc = g + (size_t)((isA ? m0 : n0) + row) * Kp + k0 + (off >> 1);
      gload_lds16(gsrc, l + cc * 1024);
    }
    __syncthreads();  // compiler drains vmcnt before barrier
#pragma unroll
    for (int kk = 0; kk < 2; ++kk) {
      int woff = kk * 64 + kq * 16;
      s16x8 ah[FM], al[FM], bh[FN], bl[FN];
#pragma unroll
      for (int f = 0; f < FM; ++f) {
        int row = wr * WM + f * 16 + r16;
        int o = woff ^ ((row & 7) << 4);
        ah[f] = *(const s16x8*)(AshC + row * 128 + o);
        if (SPLIT) al[f] = *(const s16x8*)(AslC + row * 128 + o);
      }
#pragma unroll
      for (int gg = 0; gg < FN; ++gg) {
        int row = wc * WN + gg * 16 + r16;
        int o = woff ^ ((row & 7) << 4);
        bh[gg] = *(const s16x8*)(BshC + row * 128 + o);
        if (SPLIT) bl[gg] = *(const s16x8*)(BslC + row * 128 + o);
      }
#pragma unroll
      for (int f = 0; f < FM; ++f)
#pragma unroll
        for (int gg = 0; gg < FN; ++gg) {
          acc[f][gg] = __builtin_amdgcn_mfma_f32_16x16x32_bf16(ah[f], bh[gg], acc[f][gg], 0, 0, 0);
          if (SPLIT) {
            acc[f][gg] = __builtin_amdgcn_mfma_f32_16x16x32_bf16(ah[f], bl[gg], acc[f][gg], 0, 0, 0);
            acc[f][gg] = __builtin_amdgcn_mfma_f32_16x16x32_bf16(al[f], bh[gg], acc[f][gg], 0, 0, 0);
          }
        }
    }
  }
#pragma unroll
  for (int f = 0; f < FM; ++f)
#pragma unroll
    for (int gg = 0; gg < FN; ++gg)
#pragma unroll
      for (int r = 0; r < 4; ++r) {
        int m = m0 + wr * WM + f * 16 + (lane >> 4) * 4 + r;
        int n = n0 + wc * WN + gg * 16 + r16;
        if (m >= M || n >= Nw) continue;
        float v = (n < N) ? acc[f][gg][r] : 0.f;
        size_t idx = (size_t)m * ldc + n;
        if (SPLITK) {
          size_t pidx = (size_t)bz * M * ldc + idx;
          if (PB16) partb[pidx] = f2bf(v);
          else      part[pidx] = v;
        } else {
          if (BIAS && n < N) v += bias[n];
          if (RELU) v = fmaxf(v, 0.f);
          if (OMODE == 0) Cf[idx] = v;
          else if (OMODE == 1) {
            short h = f2bf(v);
            Ch[idx] = h;
            Cl[idx] = f2bf(v - bf2f(h));
          } else if (OMODE == 2) {
            Ch[idx] = f2bf(v);
          } else {  // OMODE 3: f32 + bf16 hi/lo
            Cf[idx] = v;
            short h = f2bf(v);
            Ch[idx] = h;
            Cl[idx] = f2bf(v - bf2f(h));
          }
        }
      }
}

// ---------------- standalone GEMM wrapper ----------------
template <int BM, int BN, int WR, int WC, bool SPLIT, bool RELU, bool BIAS, int OMODE,
          bool SPLITK, bool PB16>
__global__ __launch_bounds__(WR * WC * 64) void gemm_mx(
    const short* __restrict__ Ah, const short* __restrict__ Al,
    const short* __restrict__ Bh, const short* __restrict__ Bl,
    const float* __restrict__ bias,
    float* __restrict__ Cf, short* __restrict__ Ch, short* __restrict__ Cl,
    float* __restrict__ part, short* __restrict__ partb, int KS,
    int M, int N, int Kp, int ldc, int Nw) {
  __shared__ char smem_s[(BM + BN) * 128 * (SPLIT ? 2 : 1)];
  int gx = gridDim.x, gy = gridDim.y, gz = gridDim.z;
  int fid = (blockIdx.z * gy + blockIdx.y) * gx + blockIdx.x;
  int wg = xcd_remap(fid, gx * gy * gz);
  int bx = wg % gx, byz = wg / gx;
  int by = byz % gy, bz = byz / gy;
  gemm_body<BM, BN, WR, WC, SPLIT, RELU, BIAS, OMODE, SPLITK, PB16>(
      smem_s, bx, by, bz, Ah, Al, Bh, Bl, bias, Cf, Ch, Cl, part, partb, KS,
      M, N, Kp, ldc, Nw);
}

// ---------------- fused head: e1 (z=4) + proj1 (direct bf16) + qenc ----------------
// [0,800): e1 image part, 128x64 4x2 SPLIT z=4 KS=576 -> f32 partE
// [800,1200): proj1, 128x128 2x4, z=1 DIRECT bf16 -> proj1b
// [1200,1216): qenc, 32x64 2x4 SPLIT, OMODE 3 -> qenc + qeh/qel
#define E1B 800
#define P1B 400
#define QEB 16
__global__ __launch_bounds__(512) void fused_head(
    const short* __restrict__ imgb, const short* __restrict__ imgl,
    const short* __restrict__ we1ah, const short* __restrict__ we1al,
    float* __restrict__ partE,
    const short* __restrict__ cw1t, short* __restrict__ proj1b,
    const short* __restrict__ qh, const short* __restrict__ ql,
    const short* __restrict__ wlph, const short* __restrict__ wlpl,
    const float* __restrict__ b_lproj, float* __restrict__ qenc,
    short* __restrict__ qeh, short* __restrict__ qel) {
  extern __shared__ char smem[];
  int fid = blockIdx.x;
  if (fid < E1B) {
    int wg = xcd_remap(fid, E1B);
    int gx = COMB_ / 64;                 // 8
    int bx = wg % gx, t = wg / gx;
    int by = t % (B_ * KOBJ / 128), bz = t / (B_ * KOBJ / 128);
    gemm_body<128, 64, 4, 2, true, false, false, 0, true, false>(
        smem, bx, by, bz, imgb, imgl, we1ah, we1al, nullptr,
        nullptr, nullptr, nullptr, partE, nullptr, 576,
        B_ * KOBJ, COMB_, KP1, COMB_, COMB_);
  } else if (fid < E1B + P1B) {
    int wg = xcd_remap(fid - E1B, P1B);
    int gx = 2 * HID_ / 128;             // 16
    int bx = wg % gx, by = wg / gx;
    gemm_body<128, 128, 2, 4, false, false, false, 2, false, false>(
        smem, bx, by, 0, imgb, nullptr, cw1t, nullptr, nullptr,
        nullptr, proj1b, nullptr, nullptr, nullptr, 0,
        B_ * KOBJ, 2 * HID_, KP1, 2 * HID_, 2 * HID_);
  } else {
    int bx = fid - E1B - P1B;            // 16 blocks, N tiles of 64
    gemm_body<32, 64, 2, 4, true, false, true, 3, false, false>(
        smem, bx, 0, 0, qh, ql, wlph, wlpl, b_lproj,
        qenc, qeh, qel, nullptr, nullptr, 0,
        B_, HID_, EMB_, HID_, HID_);
  }
}

// ---------------- split-K reduce (float4/short4-vectorized) ----------------
template <int OMODE, bool RELU, bool BIAS, bool BCAST, bool PB16>
__global__ void reduce_split(const float* __restrict__ part, const short* __restrict__ partb,
                             int SK, size_t pstride,
                             const float* __restrict__ bias, const float* __restrict__ bcast,
                             int bcols, float* __restrict__ Cf, short* __restrict__ Ch,
                             short* __restrict__ Cl, int M, int N, int ldIn, int ldOut) {
  int idx4 = blockIdx.x * 256 + threadIdx.x;
  int ld4 = ldIn >> 2;
  if (idx4 >= M * ld4) return;
  int m = idx4 / ld4;
  int n = (idx4 - m * ld4) << 2;
  size_t base = (size_t)m * ldIn + n;
  float a[4] = {0.f, 0.f, 0.f, 0.f};
  for (int s = 0; s < SK; ++s) {
    if (PB16) {
      short4 p = *(const short4*)(partb + (size_t)s * pstride + base);
      const short* pp = (const short*)&p;
#pragma unroll
      for (int j = 0; j < 4; ++j) a[j] += bf2f(pp[j]);
    } else {
      float4 p = *(const float4*)(part + (size_t)s * pstride + base);
      a[0] += p.x; a[1] += p.y; a[2] += p.z; a[3] += p.w;
    }
  }
#pragma unroll
  for (int j = 0; j < 4; ++j) {
    int nn = n + j;
    if (nn < N) {
      if (BCAST) a[j] += bcast[(size_t)(m / KOBJ) * bcols + nn];
      if (BIAS) a[j] += bias[nn];
    }
    if (RELU) a[j] = fmaxf(a[j], 0.f);
  }
  if (n >= ldOut) return;
  size_t o = (size_t)m * ldOut + n;
  if (OMODE == 0) {
    *(float4*)(Cf + o) = make_float4(a[0], a[1], a[2], a[3]);
  } else if (OMODE == 1) {
    short4 hh, ll;
    short* hp = (short*)&hh; short* lp = (short*)&ll;
#pragma unroll
    for (int j = 0; j < 4; ++j) {
      short h = f2bf(a[j]);
      hp[j] = h;
      lp[j] = f2bf(a[j] - bf2f(h));
    }
    *(short4*)(Ch + o) = hh;
    *(short4*)(Cl + o) = ll;
  } else {
    short4 hh;
    short* hp = (short*)&hh;
#pragma unroll
    for (int j = 0; j < 4; ++j) hp[j] = f2bf(a[j]);
    *(short4*)(Ch + o) = hh;
  }
}

// ---------------- adj fused: inline h2 = relu(sum partE + b_e2) -> LDS -> Gram MFMA ----
// One block per batch, 8 waves. h2h/h2l never touch global memory: the e2 partials
// are reduced straight into the swizzled LDS staging layout the MFMA fragments read.
__global__ __launch_bounds__(512) void adj_fused(
    const float* __restrict__ partE, const float* __restrict__ b_e2,
    float* __restrict__ adj) {
  __shared__ short Ash[128 * 64];
  __shared__ short Asl[128 * 64];
  int tid = threadIdx.x, wave = tid >> 6, lane = tid & 63;
  int wr = wave >> 2, wc = wave & 3;        // 2x4 wave grid: WM=64, WN=32
  int r16 = lane & 15, kq = lane >> 4;
  int b = blockIdx.x;
  const size_t pstride = (size_t)B_ * KOBJ * COMB_;
  f32x4 acc[4][2] = {};
  for (int k0 = 0; k0 < COMB_; k0 += 64) {
    __syncthreads();
    // ---- inline reduce: h2 chunk rows 0..127 (>=KOBJ zero), cols [k0,k0+64) ----
    for (int gidx = tid; gidx < 128 * 16; gidx += 512) {
      int r = gidx >> 4;            // 0..127
      int cg = gidx & 15;           // 4-col group
      int col = k0 + cg * 4;
      short4 hh = {0, 0, 0, 0}, ll = {0, 0, 0, 0};
      if (r < KOBJ) {
        size_t base = ((size_t)(b * KOBJ + r)) * COMB_ + col;
        float4 s0 = *(const float4*)(partE + base);
        float4 s1 = *(const float4*)(partE + pstride + base);
        float4 s2 = *(const float4*)(partE + 2 * pstride + base);
        float4 s3 = *(const float4*)(partE + 3 * pstride + base);
        float a[4] = {s0.x + s1.x + s2.x + s3.x, s0.y + s1.y + s2.y + s3.y,
                      s0.z + s1.z + s2.z + s3.z, s0.w + s1.w + s2.w + s3.w};
        short* hp = (short*)&hh;
        short* lp = (short*)&ll;
#pragma unroll
        for (int j = 0; j < 4; ++j) {
          float v = fmaxf(a[j] + b_e2[col + j], 0.f);
          short h = f2bf(v);
          hp[j] = h;
          lp[j] = f2bf(v - bf2f(h));
        }
      }
      int off = (cg * 8) ^ ((r & 7) << 4);  // swizzled byte offset within 128B row
      *(short4*)((char*)Ash + r * 128 + off) = hh;
      *(short4*)((char*)Asl + r * 128 + off) = ll;
    }
    __syncthreads();
    // ---- Gram MFMA on the chunk ----
#pragma unroll
    for (int kk = 0; kk < 2; ++kk) {
      int woff = kk * 64 + kq * 16;
      s16x8 ah[4], al[4], bh[2], bl[2];
#pragma unroll
      for (int f = 0; f < 4; ++f) {
        int row = wr * 64 + f * 16 + r16;
        int o = woff ^ ((row & 7) << 4);
        ah[f] = *(const s16x8*)((const char*)Ash + row * 128 + o);
        al[f] = *(const s16x8*)((const char*)Asl + row * 128 + o);
      }
#pragma unroll
      for (int g = 0; g < 2; ++g) {
        int row = wc * 32 + g * 16 + r16;
        int o = woff ^ ((row & 7) << 4);
        bh[g] = *(const s16x8*)((const char*)Ash + row * 128 + o);
        bl[g] = *(const s16x8*)((const char*)Asl + row * 128 + o);
      }
#pragma unroll
      for (int f = 0; f < 4; ++f)
#pragma unroll
        for (int g = 0; g < 2; ++g) {
          acc[f][g] = __builtin_amdgcn_mfma_f32_16x16x32_bf16(ah[f], bh[g], acc[f][g], 0, 0, 0);
          acc[f][g] = __builtin_amdgcn_mfma_f32_16x16x32_bf16(ah[f], bl[g], acc[f][g], 0, 0, 0);
          acc[f][g] = __builtin_amdgcn_mfma_f32_16x16x32_bf16(al[f], bh[g], acc[f][g], 0, 0, 0);
        }
    }
  }
#pragma unroll
  for (int f = 0; f < 4; ++f)
#pragma unroll
    for (int g = 0; g < 2; ++g)
#pragma unroll
      for (int r = 0; r < 4; ++r) {
        int m = wr * 64 + f * 16 + (lane >> 4) * 4 + r;
        int n = wc * 32 + g * 16 + r16;
        if (m < KOBJ && n < KOBJ)
          adj[((size_t)b * KOBJ + m) * KOBJ + n] = acc[f][g][r];
      }
}

// ---------------- top-k + softmax + gaussian kernel weights (800 blocks, 4 waves) -------
__global__ __launch_bounds__(256) void topk_weights_kernel(
    const float* __restrict__ adj, const float* __restrict__ cent,
    const float* __restrict__ mr1, const float* __restrict__ mt1,
    const float* __restrict__ pr1, const float* __restrict__ pt1,
    const float* __restrict__ mr2, const float* __restrict__ mt2,
    const float* __restrict__ pr2, const float* __restrict__ pt2,
    int* __restrict__ topi, float* __restrict__ c1, float* __restrict__ c2) {
  int row = blockIdx.x * 4 + (threadIdx.x >> 6);
  int lane = threadIdx.x & 63;
  int b = row / KOBJ, k = row % KOBJ;
  const float* ar = adj + (size_t)row * KOBJ;
  float v0 = (lane < KOBJ) ? ar[lane] : -INFINITY;
  float v1 = (lane + 64 < KOBJ) ? ar[lane + 64] : -INFINITY;
  int i0 = lane, i1 = lane + 64;
  float tv[NS_];
  int ti[NS_];
#pragma unroll
  for (int s = 0; s < NS_; ++s) {
    bool p0 = (v0 > v1) || (v0 == v1 && i0 < i1);
    float bv = p0 ? v0 : v1;
    int bi = p0 ? i0 : i1;
#pragma unroll
    for (int off = 32; off > 0; off >>= 1) {
      float ov = __shfl_xor(bv, off);
      int oi = __shfl_xor(bi, off);
      if (ov > bv || (ov == bv && oi < bi)) { bv = ov; bi = oi; }
    }
    tv[s] = bv; ti[s] = bi;
    if (bi == i0) v0 = -INFINITY;
    if (bi == i1) v1 = -INFINITY;
  }
  float mx = tv[0], sum = 0.f, av[NS_];
#pragma unroll
  for (int s = 0; s < NS_; ++s) { av[s] = expf(tv[s] - mx); sum += av[s]; }
  if (lane < NS_) {
    int j = ti[lane];
    topi[(size_t)row * NS_ + lane] = j;
    float cx = cent[(b * KOBJ + k) * 2 + 0], cy = cent[(b * KOBJ + k) * 2 + 1];
    float dx = cx - cent[(b * KOBJ + j) * 2 + 0];
    float dy = cy - cent[(b * KOBJ + j) * 2 + 1];
    float rho = sqrtf(dx * dx + dy * dy);
    float th = atan2f(dx, dy);
    float w1[NK_], w2[NK_], s1 = 0.f, s2 = 0.f;
#pragma unroll
    for (int m = 0; m < NK_; ++m) {
      {
        float pr = pr1[m], pt = pt1[m], dr = rho - mr1[m];
        float wr = expf(-0.5f * dr * dr / (1e-14f + pr * pr));
        float fa = fabsf(th - mt1[m]);
        float sa = fabsf(6.283185307179586f - fa);
        float da = fminf(fa, sa);
        float wt = expf(-0.5f * da * da / (1e-14f + pt * pt));
        float w = wr * wt;
        if (w != w) w = 0.f;
        w1[m] = w; s1 += w;
      }
      {
        float pr = pr2[m], pt = pt2[m], dr = rho - mr2[m];
        float wr = expf(-0.5f * dr * dr / (1e-14f + pr * pr));
        float fa = fabsf(th - mt2[m]);
        float sa = fabsf(6.283185307179586f - fa);
        float da = fminf(fa, sa);
        float wt = expf(-0.5f * da * da / (1e-14f + pt * pt));
        float w = wr * wt;
        if (w != w) w = 0.f;
        w2[m] = w; s2 += w;
      }
    }
    float as = av[lane] / sum;
#pragma unroll
    for (int m = 0; m < NK_; ++m) {
      c1[((size_t)row * NS_ + lane) * NK_ + m] = as * (w1[m] / s1);
      c2[((size_t)row * NS_ + lane) * NK_ + m] = w2[m] / s2;
    }
  }
}

// ---------------- gather-combine (bf16 proj in), VEC cols/thread, one block/row ----------
template <int VEC, bool BF16OUT>
__global__ __launch_bounds__(256) void combine_kernel(
    const short* __restrict__ proj, const float* __restrict__ coeff,
    const int* __restrict__ topi, float* __restrict__ outf, short* __restrict__ outb,
    int N, int mshift) {
  int row = xcd_remap(blockIdx.x, gridDim.x);
  int b = row / KOBJ;
  __shared__ int ids[NS_];
  __shared__ float cs[NS_ * NK_];
  int tid = threadIdx.x;
  if (tid < NS_) ids[tid] = topi[(size_t)row * NS_ + tid];
  else if (tid >= 32 && tid < 32 + NS_ * NK_) cs[tid - 32] = coeff[(size_t)row * NS_ * NK_ + (tid - 32)];
  __syncthreads();
  int n = tid * VEC;
  if (n >= N) return;
  int m = n >> mshift;
  float acc[VEC];
#pragma unroll
  for (int j = 0; j < VEC; ++j) acc[j] = 0.f;
#pragma unroll
  for (int s = 0; s < NS_; ++s) {
    float cc = cs[s * NK_ + m];
    const short* p = proj + ((size_t)b * KOBJ + ids[s]) * N + n;
    if (VEC == 8) {
      s16x8 v = *(const s16x8*)p;
#pragma unroll
      for (int j = 0; j < 8; ++j) acc[j] = fmaf(cc, bf2f(v[j]), acc[j]);
    } else {
      short4 v = *(const short4*)p;
      const short* vp = (const short*)&v;
#pragma unroll
      for (int j = 0; j < 4; ++j) acc[j] = fmaf(cc, bf2f(vp[j]), acc[j]);
    }
  }
#pragma unroll
  for (int j = 0; j < VEC; ++j) acc[j] = fmaxf(acc[j], 0.f);
  if (BF16OUT) {
    if (VEC == 8) {
      s16x8 o;
#pragma unroll
      for (int j = 0; j < 8; ++j) o[j] = f2bf(acc[j]);
      *(s16x8*)(outb + (size_t)row * N + n) = o;
    } else {
      short4 o;
      short* op = (short*)&o;
#pragma unroll
      for (int j = 0; j < 4; ++j) op[j] = f2bf(acc[j]);
      *(short4*)(outb + (size_t)row * N + n) = o;
    }
  } else {
    if (VEC == 4) {
      *(float4*)(outf + (size_t)row * N + n) = make_float4(acc[0], acc[1], acc[2], acc[3]);
    } else {
#pragma unroll
      for (int j = 0; j < VEC; ++j) outf[(size_t)row * N + n + j] = acc[j];
    }
  }
}

// ---------------- max over k, then hh = relu(qenc) * g2max (bf16 out) ----------------
__global__ void reduce_hh_kernel(const float* __restrict__ g2, const float* __restrict__ qenc,
                                 short* __restrict__ hhb) {
  int i = blockIdx.x * blockDim.x + threadIdx.x;
  if (i >= B_ * HID_) return;
  int b = i >> 10, n = i & (HID_ - 1);
  const float* p = g2 + (size_t)b * KOBJ * HID_ + n;
  float mx = -INFINITY;
  for (int k = 0; k < KOBJ; ++k) mx = fmaxf(mx, p[(size_t)k * HID_]);
  hhb[i] = f2bf(fmaxf(qenc[i], 0.f) * mx);
}

extern "C" void kernel_launch(void* const* d_in, const int* in_sizes, int n_in,
                              void* d_out, int out_size, void* d_ws, size_t ws_size,
                              hipStream_t stream) {
  const float* question = (const float*)d_in[0];
  const float* image    = (const float*)d_in[1];
  const float* W_lproj  = (const float*)d_in[3];
  const float* b_lproj  = (const float*)d_in[4];
  const float* W_e1     = (const float*)d_in[5];
  const float* b_e1     = (const float*)d_in[6];
  const float* W_e2     = (const float*)d_in[7];
  const float* b_e2     = (const float*)d_in[8];
  const float* conv_w1  = (const float*)d_in[9];
  const float* mr1 = (const float*)d_in[10];
  const float* mt1 = (const float*)d_in[11];
  const float* pr1 = (const float*)d_in[12];
  const float* pt1 = (const float*)d_in[13];
  const float* conv_w2  = (const float*)d_in[14];
  const float* mr2 = (const float*)d_in[15];
  const float* mt2 = (const float*)d_in[16];
  const float* pr2 = (const float*)d_in[17];
  const float* pt2 = (const float*)d_in[18];
  const float* W_o1 = (const float*)d_in[19];
  const float* b_o1 = (const float*)d_in[20];
  const float* W_o2 = (const float*)d_in[21];
  const float* b_o2 = (const float*)d_in[22];

  float* out = (float*)d_out;
  float* logits = out;               // [32,3000]
  float* adj = out + B_ * OUT_;      // [32,100,100]

  char* ws = (char*)d_ws;
  size_t off = 0;
  auto alloc = [&](size_t bytes) { char* p = ws + off; off += (bytes + 255) & ~((size_t)255); return p; };
  float* qenc  = (float*)alloc((size_t)B_ * HID_ * 4);
  short* qh    = (short*)alloc((size_t)B_ * EMB_ * 2);
  short* ql    = (short*)alloc((size_t)B_ * EMB_ * 2);
  short* qeh   = (short*)alloc((size_t)B_ * HID_ * 2);
  short* qel   = (short*)alloc((size_t)B_ * HID_ * 2);
  short* wlph  = (short*)alloc((size_t)EMB_ * HID_ * 2);
  short* wlpl  = (short*)alloc((size_t)EMB_ * HID_ * 2);
  short* we1ah = (short*)alloc((size_t)COMB_ * KP1 * 2);
  short* we1al = (short*)alloc((size_t)COMB_ * KP1 * 2);
  short* we1bh = (short*)alloc((size_t)COMB_ * HID_ * 2);
  short* we1bl = (short*)alloc((size_t)COMB_ * HID_ * 2);
  short* we2h  = (short*)alloc((size_t)COMB_ * COMB_ * 2);
  short* we2l  = (short*)alloc((size_t)COMB_ * COMB_ * 2);
  float* q1    = (float*)alloc((size_t)B_ * COMB_ * 4);
  short* h1h   = (short*)alloc((size_t)B_ * KOBJ * COMB_ * 2);
  short* h1l   = (short*)alloc((size_t)B_ * KOBJ * COMB_ * 2);
  float* cent  = (float*)alloc((size_t)B_ * KOBJ * 2 * 4);
  int*   topi  = (int*)alloc((size_t)B_ * KOBJ * NS_ * 4);
  float* c1    = (float*)alloc((size_t)B_ * KOBJ * NS_ * NK_ * 4);
  float* c2    = (float*)alloc((size_t)B_ * KOBJ * NS_ * NK_ * 4);
  short* imgb  = (short*)alloc((size_t)B_ * KOBJ * KP1 * 2);
  short* imgl  = (short*)alloc((size_t)B_ * KOBJ * KP1 * 2);
  short* cw1t  = (short*)alloc((size_t)(2 * HID_) * KP1 * 2);
  short* cw2t  = (short*)alloc((size_t)HID_ * KP2 * 2);
  short* proj1b = (short*)alloc((size_t)B_ * KOBJ * 2 * HID_ * 2);
  short* g1b   = (short*)alloc((size_t)B_ * KOBJ * KP2 * 2);
  short* proj2b = (short*)alloc((size_t)B_ * KOBJ * HID_ * 2);
  float* g2    = (float*)alloc((size_t)B_ * KOBJ * HID_ * 4);
  short* hhb   = (short*)alloc((size_t)B_ * HID_ * 2);
  short* wo1t  = (short*)alloc((size_t)NO_P * HID_ * 2);
  short* wo2t  = (short*)alloc((size_t)NO_P * KO2 * 2);
  short* h1ob  = (short*)alloc((size_t)B_ * KO2 * 2);
  float* partE = (float*)alloc((size_t)4 * B_ * KOBJ * COMB_ * 4);      // f32 partials
  short* partP = (short*)alloc((size_t)4 * B_ * KOBJ * HID_ * 2);       // bf16 partials (proj2)
  (void)ws_size; (void)in_sizes; (void)n_in; (void)out_size;

  dim3 blk(256), blk512(512);

  // ---- ONE dispatch: weight transposes + input cvt + centres ----
  {
    TDs ds;
    int cum = 0;
    auto set = [&](int i, const float* in, short* oh, short* ol, int K, int N, int Kp,
                   int OPM, int nnt, int split, int conv) {
      int nkt = Kp / 64;
      cum += nkt * nnt;
      ds.d[i] = TD{in, oh, ol, K, N, Kp, OPM, nkt, split, conv, cum};
    };
    set(0, W_lproj, wlph, wlpl, EMB_, HID_, EMB_, 0, HID_ / 64, 1, 0);
    set(1, W_e1, we1ah, we1al, FEAT_, COMB_, KP1, 0, COMB_ / 64, 1, 0);
    set(2, W_e1 + (size_t)FEAT_ * COMB_, we1bh, we1bl, HID_, COMB_, HID_, 0, COMB_ / 64, 1, 0);
    set(3, W_e2, we2h, we2l, COMB_, COMB_, COMB_, 0, COMB_ / 64, 1, 0);
    set(4, conv_w1, cw1t, nullptr, FEAT_, 2 * HID_, KP1, 2 * HID_ / NK_, 2 * HID_ / 64, 0, 1);
    set(5, conv_w2, cw2t, nullptr, 2 * HID_, HID_, KP2, HID_ / NK_, HID_ / 64, 0, 1);
    set(6, W_o1, wo1t, nullptr, HID_, OUT_, HID_, 0, NO_P / 64, 0, 0);
    set(7, W_o2, wo2t, nullptr, OUT_, OUT_, KO2, 0, NO_P / 64, 0, 0);
    prep_all<<<dim3(cum + IMG_BLKS + Q_BLKS + C_BLKS), blk, 0, stream>>>(
        ds, cum, image, question, imgb, imgl, qh, ql, cent);
  }

  // ---- FUSED head: e1 (z=4 f32 partials, KS=576) + proj1 (direct bf16) + qenc ----
  fused_head<<<dim3(E1B + P1B + QEB), blk512, 49152, stream>>>(
      imgb, imgl, we1ah, we1al, partE, cw1t, proj1b,
      qh, ql, wlph, wlpl, b_lproj, qenc, qeh, qel);
  // ---- q1 = qenc @ We1[2052:] (split, no bias) ----
  gemm_mx<32, 64, 2, 2, true, false, false, 0, false, false><<<dim3(COMB_ / 64, 1, 1), blk, 0, stream>>>(
      qeh, qel, we1bh, we1bl, nullptr, q1, nullptr, nullptr, nullptr, nullptr, 0, B_, COMB_, HID_, COMB_, COMB_);
  // ---- h1 = relu(sum + q1[bcast] + b_e1), bf16 hi/lo (SK=4) ----
  reduce_split<1, true, true, true, false><<<dim3(B_ * KOBJ * COMB_ / 4 / 256), blk, 0, stream>>>(
      partE, nullptr, 4, (size_t)B_ * KOBJ * COMB_, b_e1, q1, COMB_, nullptr, h1h, h1l,
      B_ * KOBJ, COMB_, COMB_, COMB_);
  // ---- e2: split-K partials f32 (z=4, KS=128) ----
  gemm_mx<128, 64, 4, 2, true, false, false, 0, true, false><<<dim3(COMB_ / 64, B_ * KOBJ / 128, 4), blk512, 0, stream>>>(
      h1h, h1l, we2h, we2l, nullptr, nullptr, nullptr, nullptr, partE, nullptr, 128,
      B_ * KOBJ, COMB_, COMB_, COMB_, COMB_);
  // ---- adj: inline h2 reduce + Gram MFMA (h2 never hits global) ----
  adj_fused<<<dim3(B_), blk512, 0, stream>>>(partE, b_e2, adj);
  topk_weights_kernel<<<dim3(B_ * KOBJ / 4), blk, 0, stream>>>(
      adj, cent, mr1, mt1, pr1, pt1, mr2, mt2, pr2, pt2, topi, c1, c2);
  // ---- conv path (proj1b ready from fused head) ----
  combine_kernel<8, true><<<dim3(B_ * KOBJ), blk, 0, stream>>>(
      proj1b, c1, topi, nullptr, g1b, 2 * HID_, 8);
  // ---- proj2: 128x128 2x4 z=4 bf16 partials ----
  gemm_mx<128, 128, 2, 4, false, false, false, 0, true, true><<<dim3(HID_ / 128, B_ * KOBJ / 128, 4), blk512, 0, stream>>>(
      g1b, nullptr, cw2t, nullptr, nullptr, nullptr, nullptr, nullptr, nullptr, partP, 512,
      B_ * KOBJ, HID_, KP2, HID_, HID_);
  reduce_split<2, false, false, false, true><<<dim3(B_ * KOBJ * HID_ / 4 / 256), blk, 0, stream>>>(
      nullptr, partP, 4, (size_t)B_ * KOBJ * HID_, nullptr, nullptr, 0, nullptr, proj2b, nullptr,
      B_ * KOBJ, HID_, HID_, HID_);
  combine_kernel<4, false><<<dim3(B_ * KOBJ), blk, 0, stream>>>(
      proj2b, c2, topi, g2, nullptr, HID_, 7);
  // ---- tail ----
  reduce_hh_kernel<<<dim3((B_ * HID_ + 255) / 256), blk, 0, stream>>>(g2, qenc, hhb);
  // o1: split-K z=16, KS=64
  gemm_mx<32, 128, 1, 4, false, false, false, 0, true, false><<<dim3(NO_P / 128, 1, 16), blk, 0, stream>>>(
      hhb, nullptr, wo1t, nullptr, nullptr, nullptr, nullptr, nullptr, partE, nullptr, 64,
      B_, OUT_, HID_, KO2, KO2);
  reduce_split<2, true, true, false, false><<<dim3((B_ * KO2 / 4 + 255) / 256), blk, 0, stream>>>(
      partE, nullptr, 16, (size_t)B_ * KO2, b_o1, nullptr, 0, nullptr, h1ob, nullptr,
      B_, OUT_, KO2, KO2);
  // o2: split-K z=16, KS=192
  gemm_mx<32, 128, 1, 4, false, false, false, 0, true, false><<<dim3(NO_P / 128, 1, 16), blk, 0, stream>>>(
      h1ob, nullptr, wo2t, nullptr, nullptr, nullptr, nullptr, nullptr, partE, nullptr, 192,
      B_, OUT_, KO2, KO2, KO2);
  reduce_split<0, false, true, false, false><<<dim3((B_ * KO2 / 4 + 255) / 256), blk, 0, stream>>>(
      partE, nullptr, 16, (size_t)B_ * KO2, b_o2, nullptr, 0, logits, nullptr, nullptr,
      B_, OUT_, KO2, OUT_);
}

// Round 20
// 291.205 us; speedup vs baseline: 1.0214x; 1.0214x over previous
//
#include <hip/hip_runtime.h>
#include <math.h>
#include <stdint.h>

#define B_    32
#define KOBJ  100
#define NS_   16
#define NK_   8
#define EMB_  1024
#define FEAT_ 2052
#define HID_  1024
#define OUT_  3000
#define COMB_ 512

#define KP1   2112   // FEAT_ padded to 64 (image rows / We1a rows)
#define KP2   2048   // 2*HID_
#define NO_P  3072   // OUT_ padded to 128 (N of o1/o2)
#define KO2   3008   // OUT_ padded to 64 (K of o2)

typedef __attribute__((ext_vector_type(8))) short s16x8;
typedef __attribute__((ext_vector_type(4))) float f32x4;

__device__ inline short f2bf(float f) {
  uint32_t u = __builtin_bit_cast(uint32_t, f);
  u = (u + 0x7fff + ((u >> 16) & 1)) >> 16;  // RNE
  return (short)u;
}
__device__ inline float bf2f(short s) {
  uint32_t u = ((uint32_t)(uint16_t)s) << 16;
  return __builtin_bit_cast(float, u);
}
__device__ inline void gload_lds16(const void* g, void* l) {
  __builtin_amdgcn_global_load_lds(
      (const __attribute__((address_space(1))) void*)g,
      (__attribute__((address_space(3))) void*)l, 16, 0, 0);
}
// XCD-aware bijective remap (m204): consecutive wg cluster on one XCD
__device__ inline int xcd_remap(int fid, int nwg) {
  int q = nwg >> 3, r = nwg & 7;
  int x = fid & 7, l = fid >> 3;
  return (x < r ? x * (q + 1) : r * (q + 1) + (x - r) * q) + l;
}

#define IMG_CHUNKS (B_ * KOBJ * (KP1 / 8))
#define IMG_BLKS   ((IMG_CHUNKS + 255) / 256)
#define Q_CHUNKS   (B_ * (EMB_ / 8))
#define Q_BLKS     ((Q_CHUNKS + 255) / 256)
#define C_BLKS     ((B_ * KOBJ + 255) / 256)

__device__ inline void cvt8_split(const float* __restrict__ in, short* __restrict__ oh,
                                  short* __restrict__ ol, int K, int Kp, int idx) {
  int row = idx / (Kp / 8), c8 = (idx % (Kp / 8)) * 8;
  float f[8];
  if (c8 + 8 <= K) {
    const float* src = in + (size_t)row * K + c8;
    float4 a = *(const float4*)src;
    float4 b = *(const float4*)(src + 4);
    f[0] = a.x; f[1] = a.y; f[2] = a.z; f[3] = a.w;
    f[4] = b.x; f[5] = b.y; f[6] = b.z; f[7] = b.w;
  } else {
#pragma unroll
    for (int i = 0; i < 8; ++i) {
      int k = c8 + i;
      f[i] = (k < K) ? in[(size_t)row * K + k] : 0.f;
    }
  }
  s16x8 vh, vl;
#pragma unroll
  for (int i = 0; i < 8; ++i) {
    short h = f2bf(f[i]);
    vh[i] = h;
    vl[i] = f2bf(f[i] - bf2f(h));
  }
  *(s16x8*)(oh + (size_t)row * Kp + c8) = vh;
  *(s16x8*)(ol + (size_t)row * Kp + c8) = vl;
}

// ---------------- ONE dispatch: all weight transposes + input cvt + centres ----------------
struct TD {
  const float* in; short* oh; short* ol;
  int K, N, Kp, OPM, nkt, split, conv, cum;
};
struct TDs { TD d[8]; };

__global__ __launch_bounds__(256) void prep_all(
    TDs ds, int tcum,
    const float* __restrict__ image, const float* __restrict__ question,
    short* __restrict__ imgb, short* __restrict__ imgl,
    short* __restrict__ qh, short* __restrict__ ql, float* __restrict__ cent) {
  int bid = blockIdx.x, t = threadIdx.x;
  if (bid >= tcum) {
    int bb = bid - tcum;
    if (bb < IMG_BLKS) {
      int idx = bb * 256 + t;
      if (idx < IMG_CHUNKS) cvt8_split(image, imgb, imgl, FEAT_, KP1, idx);
    } else if (bb < IMG_BLKS + Q_BLKS) {
      int idx = (bb - IMG_BLKS) * 256 + t;
      if (idx < Q_CHUNKS) cvt8_split(question, qh, ql, EMB_, EMB_, idx);
    } else {
      int i = (bb - IMG_BLKS - Q_BLKS) * 256 + t;
      if (i < B_ * KOBJ) {
        const float* bbx = image + (size_t)i * FEAT_ + (FEAT_ - 4);
        cent[i * 2 + 0] = 0.5f * (bbx[0] + bbx[2]);
        cent[i * 2 + 1] = 0.5f * (bbx[1] + bbx[3]);
      }
    }
    return;
  }
  __shared__ float s[64][65];
  int i = 0;
  while (i < 7 && bid >= ds.d[i].cum) ++i;
  const TD& d = ds.d[i];
  int local = bid - (i ? ds.d[i - 1].cum : 0);
  int k0 = (local % d.nkt) * 64, n0 = (local / d.nkt) * 64;
  int rr = t >> 4, c4 = (t & 15) * 4;
  bool fullN = d.conv || (n0 + 64 <= d.N);
#pragma unroll
  for (int p = 0; p < 4; ++p) {
    int row = p * 16 + rr;
    int kg = k0 + row;
    float v0 = 0.f, v1 = 0.f, v2 = 0.f, v3 = 0.f;
    if (kg < d.K) {
      const float* src = d.conv
          ? d.in + ((size_t)(n0 / d.OPM) * d.K + kg) * d.OPM + (n0 % d.OPM) + c4
          : d.in + (size_t)kg * d.N + n0 + c4;
      if (fullN) {
        float4 v = *(const float4*)src;
        v0 = v.x; v1 = v.y; v2 = v.z; v3 = v.w;
      } else {
        int nb = n0 + c4;
        if (nb + 0 < d.N) v0 = src[0];
        if (nb + 1 < d.N) v1 = src[1];
        if (nb + 2 < d.N) v2 = src[2];
        if (nb + 3 < d.N) v3 = src[3];
      }
    }
    s[row][c4 + 0] = v0; s[row][c4 + 1] = v1;
    s[row][c4 + 2] = v2; s[row][c4 + 3] = v3;
  }
  __syncthreads();
  int nl = t >> 2, kc = (t & 3) << 4;
#pragma unroll
  for (int half = 0; half < 2; ++half) {
    s16x8 vh, vl;
#pragma unroll
    for (int j = 0; j < 8; ++j) {
      float f = s[kc + half * 8 + j][nl];
      short h = f2bf(f);
      vh[j] = h;
      vl[j] = f2bf(f - bf2f(h));
    }
    size_t o = (size_t)(n0 + nl) * d.Kp + k0 + kc + half * 8;
    *(s16x8*)(d.oh + o) = vh;
    if (d.split) *(s16x8*)(d.ol + o) = vl;
  }
}

// ---------------- MFMA GEMM body (device fn on caller-provided LDS) ----------------
// NOTE: when SPLITK, KS must be a MULTIPLE OF 64 (non-multiple double-counts — R13 bug).
template <int BM, int BN, int WR, int WC, bool SPLIT, bool RELU, bool BIAS, int OMODE,
          bool SPLITK, bool PB16>
__device__ __forceinline__ void gemm_body(
    char* smem, int bx, int by, int bz,
    const short* __restrict__ Ah, const short* __restrict__ Al,
    const short* __restrict__ Bh, const short* __restrict__ Bl,
    const float* __restrict__ bias,
    float* __restrict__ Cf, short* __restrict__ Ch, short* __restrict__ Cl,
    float* __restrict__ part, short* __restrict__ partb, int KS,
    int M, int N, int Kp, int ldc, int Nw) {
  constexpr int NWV = WR * WC;
  constexpr int WM = BM / WR, WN = BN / WC;
  constexpr int FM = WM / 16, FN = WN / 16;
  constexpr int ACH = BM / 8, BCH = BN / 8;
  constexpr int NCH = (ACH + BCH) * (SPLIT ? 2 : 1);
  char* AshC = smem;
  char* BshC = smem + BM * 128;
  char* AslC = smem + (BM + BN) * 128;
  char* BslC = smem + (2 * BM + BN) * 128;
  int tid = threadIdx.x, wave = tid >> 6, lane = tid & 63;
  int wr = wave / WC, wc = wave % WC;
  int r16 = lane & 15, kq = lane >> 4;
  int m0 = by * BM, n0 = bx * BN;
  int kb = SPLITK ? bz * KS : 0;
  int ke = SPLITK ? (kb + KS < Kp ? kb + KS : Kp) : Kp;
  f32x4 acc[FM][FN] = {};

  for (int k0 = kb; k0 < ke; k0 += 64) {
    __syncthreads();
    for (int c = wave; c < NCH; c += NWV) {
      int cc = c;
      const short* g;
      char* l;
      bool isA;
      if (cc < ACH) { isA = true; g = Ah; l = AshC; }
      else if (SPLIT && cc < 2 * ACH) { cc -= ACH; isA = true; g = Al; l = AslC; }
      else {
        cc -= SPLIT ? 2 * ACH : ACH;
        if (cc < BCH) { isA = false; g = Bh; l = BshC; }
        else { cc -= BCH; isA = false; g = Bl; l = BslC; }
      }
      int Lb = cc * 1024 + lane * 16;
      int row = Lb >> 7;
      int off = (Lb & 127) ^ ((row & 7) << 4);
      const short* gsrc = g + (size_t)((isA ? m0 : n0) + row) * Kp + k0 + (off >> 1);
      gload_lds16(gsrc, l + cc * 1024);
    }
    __syncthreads();  // compiler drains vmcnt before barrier
#pragma unroll
    for (int kk = 0; kk < 2; ++kk) {
      int woff = kk * 64 + kq * 16;
      s16x8 ah[FM], al[FM], bh[FN], bl[FN];
#pragma unroll
      for (int f = 0; f < FM; ++f) {
        int row = wr * WM + f * 16 + r16;
        int o = woff ^ ((row & 7) << 4);
        ah[f] = *(const s16x8*)(AshC + row * 128 + o);
        if (SPLIT) al[f] = *(const s16x8*)(AslC + row * 128 + o);
      }
#pragma unroll
      for (int gg = 0; gg < FN; ++gg) {
        int row = wc * WN + gg * 16 + r16;
        int o = woff ^ ((row & 7) << 4);
        bh[gg] = *(const s16x8*)(BshC + row * 128 + o);
        if (SPLIT) bl[gg] = *(const s16x8*)(BslC + row * 128 + o);
      }
#pragma unroll
      for (int f = 0; f < FM; ++f)
#pragma unroll
        for (int gg = 0; gg < FN; ++gg) {
          acc[f][gg] = __builtin_amdgcn_mfma_f32_16x16x32_bf16(ah[f], bh[gg], acc[f][gg], 0, 0, 0);
          if (SPLIT) {
            acc[f][gg] = __builtin_amdgcn_mfma_f32_16x16x32_bf16(ah[f], bl[gg], acc[f][gg], 0, 0, 0);
            acc[f][gg] = __builtin_amdgcn_mfma_f32_16x16x32_bf16(al[f], bh[gg], acc[f][gg], 0, 0, 0);
          }
        }
    }
  }
#pragma unroll
  for (int f = 0; f < FM; ++f)
#pragma unroll
    for (int gg = 0; gg < FN; ++gg)
#pragma unroll
      for (int r = 0; r < 4; ++r) {
        int m = m0 + wr * WM + f * 16 + (lane >> 4) * 4 + r;
        int n = n0 + wc * WN + gg * 16 + r16;
        if (m >= M || n >= Nw) continue;
        float v = (n < N) ? acc[f][gg][r] : 0.f;
        size_t idx = (size_t)m * ldc + n;
        if (SPLITK) {
          size_t pidx = (size_t)bz * M * ldc + idx;
          if (PB16) partb[pidx] = f2bf(v);
          else      part[pidx] = v;
        } else {
          if (BIAS && n < N) v += bias[n];
          if (RELU) v = fmaxf(v, 0.f);
          if (OMODE == 0) Cf[idx] = v;
          else if (OMODE == 1) {
            short h = f2bf(v);
            Ch[idx] = h;
            Cl[idx] = f2bf(v - bf2f(h));
          } else if (OMODE == 2) {
            Ch[idx] = f2bf(v);
          } else {  // OMODE 3: f32 + bf16 hi/lo
            Cf[idx] = v;
            short h = f2bf(v);
            Ch[idx] = h;
            Cl[idx] = f2bf(v - bf2f(h));
          }
        }
      }
}

// ---------------- standalone GEMM wrapper ----------------
template <int BM, int BN, int WR, int WC, bool SPLIT, bool RELU, bool BIAS, int OMODE,
          bool SPLITK, bool PB16>
__global__ __launch_bounds__(WR * WC * 64) void gemm_mx(
    const short* __restrict__ Ah, const short* __restrict__ Al,
    const short* __restrict__ Bh, const short* __restrict__ Bl,
    const float* __restrict__ bias,
    float* __restrict__ Cf, short* __restrict__ Ch, short* __restrict__ Cl,
    float* __restrict__ part, short* __restrict__ partb, int KS,
    int M, int N, int Kp, int ldc, int Nw) {
  __shared__ char smem_s[(BM + BN) * 128 * (SPLIT ? 2 : 1)];
  int gx = gridDim.x, gy = gridDim.y, gz = gridDim.z;
  int fid = (blockIdx.z * gy + blockIdx.y) * gx + blockIdx.x;
  int wg = xcd_remap(fid, gx * gy * gz);
  int bx = wg % gx, byz = wg / gx;
  int by = byz % gy, bz = byz / gy;
  gemm_body<BM, BN, WR, WC, SPLIT, RELU, BIAS, OMODE, SPLITK, PB16>(
      smem_s, bx, by, bz, Ah, Al, Bh, Bl, bias, Cf, Ch, Cl, part, partb, KS,
      M, N, Kp, ldc, Nw);
}

// ---------------- fused head: e1 (z=4) + proj1 (direct bf16) + qenc ----------------
// [0,800): e1 image part, 128x64 4x2 SPLIT z=4 KS=576 -> f32 partE
// [800,1200): proj1, 128x128 2x4, z=1 DIRECT bf16 -> proj1b
// [1200,1216): qenc, 32x64 2x4 SPLIT, OMODE 3 -> qenc + qeh/qel
#define E1B 800
#define P1B 400
#define QEB 16
__global__ __launch_bounds__(512) void fused_head(
    const short* __restrict__ imgb, const short* __restrict__ imgl,
    const short* __restrict__ we1ah, const short* __restrict__ we1al,
    float* __restrict__ partE,
    const short* __restrict__ cw1t, short* __restrict__ proj1b,
    const short* __restrict__ qh, const short* __restrict__ ql,
    const short* __restrict__ wlph, const short* __restrict__ wlpl,
    const float* __restrict__ b_lproj, float* __restrict__ qenc,
    short* __restrict__ qeh, short* __restrict__ qel) {
  extern __shared__ char smem[];
  int fid = blockIdx.x;
  if (fid < E1B) {
    int wg = xcd_remap(fid, E1B);
    int gx = COMB_ / 64;                 // 8
    int bx = wg % gx, t = wg / gx;
    int by = t % (B_ * KOBJ / 128), bz = t / (B_ * KOBJ / 128);
    gemm_body<128, 64, 4, 2, true, false, false, 0, true, false>(
        smem, bx, by, bz, imgb, imgl, we1ah, we1al, nullptr,
        nullptr, nullptr, nullptr, partE, nullptr, 576,
        B_ * KOBJ, COMB_, KP1, COMB_, COMB_);
  } else if (fid < E1B + P1B) {
    int wg = xcd_remap(fid - E1B, P1B);
    int gx = 2 * HID_ / 128;             // 16
    int bx = wg % gx, by = wg / gx;
    gemm_body<128, 128, 2, 4, false, false, false, 2, false, false>(
        smem, bx, by, 0, imgb, nullptr, cw1t, nullptr, nullptr,
        nullptr, proj1b, nullptr, nullptr, nullptr, 0,
        B_ * KOBJ, 2 * HID_, KP1, 2 * HID_, 2 * HID_);
  } else {
    int bx = fid - E1B - P1B;            // 16 blocks, N tiles of 64
    gemm_body<32, 64, 2, 4, true, false, true, 3, false, false>(
        smem, bx, 0, 0, qh, ql, wlph, wlpl, b_lproj,
        qenc, qeh, qel, nullptr, nullptr, 0,
        B_, HID_, EMB_, HID_, HID_);
  }
}

// ---------------- split-K reduce (float4/short4-vectorized) ----------------
template <int OMODE, bool RELU, bool BIAS, bool BCAST, bool PB16>
__global__ void reduce_split(const float* __restrict__ part, const short* __restrict__ partb,
                             int SK, size_t pstride,
                             const float* __restrict__ bias, const float* __restrict__ bcast,
                             int bcols, float* __restrict__ Cf, short* __restrict__ Ch,
                             short* __restrict__ Cl, int M, int N, int ldIn, int ldOut) {
  int idx4 = blockIdx.x * 256 + threadIdx.x;
  int ld4 = ldIn >> 2;
  if (idx4 >= M * ld4) return;
  int m = idx4 / ld4;
  int n = (idx4 - m * ld4) << 2;
  size_t base = (size_t)m * ldIn + n;
  float a[4] = {0.f, 0.f, 0.f, 0.f};
  for (int s = 0; s < SK; ++s) {
    if (PB16) {
      short4 p = *(const short4*)(partb + (size_t)s * pstride + base);
      const short* pp = (const short*)&p;
#pragma unroll
      for (int j = 0; j < 4; ++j) a[j] += bf2f(pp[j]);
    } else {
      float4 p = *(const float4*)(part + (size_t)s * pstride + base);
      a[0] += p.x; a[1] += p.y; a[2] += p.z; a[3] += p.w;
    }
  }
#pragma unroll
  for (int j = 0; j < 4; ++j) {
    int nn = n + j;
    if (nn < N) {
      if (BCAST) a[j] += bcast[(size_t)(m / KOBJ) * bcols + nn];
      if (BIAS) a[j] += bias[nn];
    }
    if (RELU) a[j] = fmaxf(a[j], 0.f);
  }
  if (n >= ldOut) return;
  size_t o = (size_t)m * ldOut + n;
  if (OMODE == 0) {
    *(float4*)(Cf + o) = make_float4(a[0], a[1], a[2], a[3]);
  } else if (OMODE == 1) {
    short4 hh, ll;
    short* hp = (short*)&hh; short* lp = (short*)&ll;
#pragma unroll
    for (int j = 0; j < 4; ++j) {
      short h = f2bf(a[j]);
      hp[j] = h;
      lp[j] = f2bf(a[j] - bf2f(h));
    }
    *(short4*)(Ch + o) = hh;
    *(short4*)(Cl + o) = ll;
  } else {
    short4 hh;
    short* hp = (short*)&hh;
#pragma unroll
    for (int j = 0; j < 4; ++j) hp[j] = f2bf(a[j]);
    *(short4*)(Ch + o) = hh;
  }
}

// ---------------- adj[b] = h2[b] @ h2[b]^T, split-bf16 MFMA, one block/batch ----------------
__global__ __launch_bounds__(512) void adj_mfma(const short* __restrict__ Hh,
                                                const short* __restrict__ Hl,
                                                float* __restrict__ adj) {
  __shared__ short Ash[128 * 64];
  __shared__ short Asl[128 * 64];
  int tid = threadIdx.x, wave = tid >> 6, lane = tid & 63;
  int wr = wave >> 2, wc = wave & 3;        // 2x4 wave grid: WM=64, WN=32
  int r16 = lane & 15, kq = lane >> 4;
  int b = blockIdx.x;
  const short* baseh = Hh + (size_t)b * KOBJ * COMB_;
  const short* basel = Hl + (size_t)b * KOBJ * COMB_;
  f32x4 acc[4][2] = {};
  for (int k0 = 0; k0 < COMB_; k0 += 64) {
    __syncthreads();
    for (int c = wave; c < 32; c += 8) {
      int cc = c & 15;
      bool hi = c < 16;
      int Lb = cc * 1024 + lane * 16;
      int row = Lb >> 7;
      int off = (Lb & 127) ^ ((row & 7) << 4);
      const short* gsrc = (hi ? baseh : basel) + (size_t)row * COMB_ + k0 + (off >> 1);
      gload_lds16(gsrc, (char*)(hi ? Ash : Asl) + cc * 1024);
    }
    __syncthreads();
#pragma unroll
    for (int kk = 0; kk < 2; ++kk) {
      int woff = kk * 64 + kq * 16;
      s16x8 ah[4], al[4], bh[2], bl[2];
#pragma unroll
      for (int f = 0; f < 4; ++f) {
        int row = wr * 64 + f * 16 + r16;
        int o = woff ^ ((row & 7) << 4);
        ah[f] = *(const s16x8*)((const char*)Ash + row * 128 + o);
        al[f] = *(const s16x8*)((const char*)Asl + row * 128 + o);
      }
#pragma unroll
      for (int g = 0; g < 2; ++g) {
        int row = wc * 32 + g * 16 + r16;
        int o = woff ^ ((row & 7) << 4);
        bh[g] = *(const s16x8*)((const char*)Ash + row * 128 + o);
        bl[g] = *(const s16x8*)((const char*)Asl + row * 128 + o);
      }
#pragma unroll
      for (int f = 0; f < 4; ++f)
#pragma unroll
        for (int g = 0; g < 2; ++g) {
          acc[f][g] = __builtin_amdgcn_mfma_f32_16x16x32_bf16(ah[f], bh[g], acc[f][g], 0, 0, 0);
          acc[f][g] = __builtin_amdgcn_mfma_f32_16x16x32_bf16(ah[f], bl[g], acc[f][g], 0, 0, 0);
          acc[f][g] = __builtin_amdgcn_mfma_f32_16x16x32_bf16(al[f], bh[g], acc[f][g], 0, 0, 0);
        }
    }
  }
#pragma unroll
  for (int f = 0; f < 4; ++f)
#pragma unroll
    for (int g = 0; g < 2; ++g)
#pragma unroll
      for (int r = 0; r < 4; ++r) {
        int m = wr * 64 + f * 16 + (lane >> 4) * 4 + r;
        int n = wc * 32 + g * 16 + r16;
        if (m < KOBJ && n < KOBJ)
          adj[((size_t)b * KOBJ + m) * KOBJ + n] = acc[f][g][r];
      }
}

// ---------------- top-k + softmax + gaussian kernel weights (800 blocks, 4 waves) -------
__global__ __launch_bounds__(256) void topk_weights_kernel(
    const float* __restrict__ adj, const float* __restrict__ cent,
    const float* __restrict__ mr1, const float* __restrict__ mt1,
    const float* __restrict__ pr1, const float* __restrict__ pt1,
    const float* __restrict__ mr2, const float* __restrict__ mt2,
    const float* __restrict__ pr2, const float* __restrict__ pt2,
    int* __restrict__ topi, float* __restrict__ c1, float* __restrict__ c2) {
  int row = blockIdx.x * 4 + (threadIdx.x >> 6);
  int lane = threadIdx.x & 63;
  int b = row / KOBJ, k = row % KOBJ;
  const float* ar = adj + (size_t)row * KOBJ;
  float v0 = (lane < KOBJ) ? ar[lane] : -INFINITY;
  float v1 = (lane + 64 < KOBJ) ? ar[lane + 64] : -INFINITY;
  int i0 = lane, i1 = lane + 64;
  float tv[NS_];
  int ti[NS_];
#pragma unroll
  for (int s = 0; s < NS_; ++s) {
    bool p0 = (v0 > v1) || (v0 == v1 && i0 < i1);
    float bv = p0 ? v0 : v1;
    int bi = p0 ? i0 : i1;
#pragma unroll
    for (int off = 32; off > 0; off >>= 1) {
      float ov = __shfl_xor(bv, off);
      int oi = __shfl_xor(bi, off);
      if (ov > bv || (ov == bv && oi < bi)) { bv = ov; bi = oi; }
    }
    tv[s] = bv; ti[s] = bi;
    if (bi == i0) v0 = -INFINITY;
    if (bi == i1) v1 = -INFINITY;
  }
  float mx = tv[0], sum = 0.f, av[NS_];
#pragma unroll
  for (int s = 0; s < NS_; ++s) { av[s] = expf(tv[s] - mx); sum += av[s]; }
  if (lane < NS_) {
    int j = ti[lane];
    topi[(size_t)row * NS_ + lane] = j;
    float cx = cent[(b * KOBJ + k) * 2 + 0], cy = cent[(b * KOBJ + k) * 2 + 1];
    float dx = cx - cent[(b * KOBJ + j) * 2 + 0];
    float dy = cy - cent[(b * KOBJ + j) * 2 + 1];
    float rho = sqrtf(dx * dx + dy * dy);
    float th = atan2f(dx, dy);
    float w1[NK_], w2[NK_], s1 = 0.f, s2 = 0.f;
#pragma unroll
    for (int m = 0; m < NK_; ++m) {
      {
        float pr = pr1[m], pt = pt1[m], dr = rho - mr1[m];
        float wr = expf(-0.5f * dr * dr / (1e-14f + pr * pr));
        float fa = fabsf(th - mt1[m]);
        float sa = fabsf(6.283185307179586f - fa);
        float da = fminf(fa, sa);
        float wt = expf(-0.5f * da * da / (1e-14f + pt * pt));
        float w = wr * wt;
        if (w != w) w = 0.f;
        w1[m] = w; s1 += w;
      }
      {
        float pr = pr2[m], pt = pt2[m], dr = rho - mr2[m];
        float wr = expf(-0.5f * dr * dr / (1e-14f + pr * pr));
        float fa = fabsf(th - mt2[m]);
        float sa = fabsf(6.283185307179586f - fa);
        float da = fminf(fa, sa);
        float wt = expf(-0.5f * da * da / (1e-14f + pt * pt));
        float w = wr * wt;
        if (w != w) w = 0.f;
        w2[m] = w; s2 += w;
      }
    }
    float as = av[lane] / sum;
#pragma unroll
    for (int m = 0; m < NK_; ++m) {
      c1[((size_t)row * NS_ + lane) * NK_ + m] = as * (w1[m] / s1);
      c2[((size_t)row * NS_ + lane) * NK_ + m] = w2[m] / s2;
    }
  }
}

// ---------------- gather-combine (bf16 proj in), VEC cols/thread, one block/row ----------
template <int VEC, bool BF16OUT>
__global__ __launch_bounds__(256) void combine_kernel(
    const short* __restrict__ proj, const float* __restrict__ coeff,
    const int* __restrict__ topi, float* __restrict__ outf, short* __restrict__ outb,
    int N, int mshift) {
  int row = xcd_remap(blockIdx.x, gridDim.x);
  int b = row / KOBJ;
  __shared__ int ids[NS_];
  __shared__ float cs[NS_ * NK_];
  int tid = threadIdx.x;
  if (tid < NS_) ids[tid] = topi[(size_t)row * NS_ + tid];
  else if (tid >= 32 && tid < 32 + NS_ * NK_) cs[tid - 32] = coeff[(size_t)row * NS_ * NK_ + (tid - 32)];
  __syncthreads();
  int n = tid * VEC;
  if (n >= N) return;
  int m = n >> mshift;
  float acc[VEC];
#pragma unroll
  for (int j = 0; j < VEC; ++j) acc[j] = 0.f;
#pragma unroll
  for (int s = 0; s < NS_; ++s) {
    float cc = cs[s * NK_ + m];
    const short* p = proj + ((size_t)b * KOBJ + ids[s]) * N + n;
    if (VEC == 8) {
      s16x8 v = *(const s16x8*)p;
#pragma unroll
      for (int j = 0; j < 8; ++j) acc[j] = fmaf(cc, bf2f(v[j]), acc[j]);
    } else {
      short4 v = *(const short4*)p;
      const short* vp = (const short*)&v;
#pragma unroll
      for (int j = 0; j < 4; ++j) acc[j] = fmaf(cc, bf2f(vp[j]), acc[j]);
    }
  }
#pragma unroll
  for (int j = 0; j < VEC; ++j) acc[j] = fmaxf(acc[j], 0.f);
  if (BF16OUT) {
    if (VEC == 8) {
      s16x8 o;
#pragma unroll
      for (int j = 0; j < 8; ++j) o[j] = f2bf(acc[j]);
      *(s16x8*)(outb + (size_t)row * N + n) = o;
    } else {
      short4 o;
      short* op = (short*)&o;
#pragma unroll
      for (int j = 0; j < 4; ++j) op[j] = f2bf(acc[j]);
      *(short4*)(outb + (size_t)row * N + n) = o;
    }
  } else {
    if (VEC == 4) {
      *(float4*)(outf + (size_t)row * N + n) = make_float4(acc[0], acc[1], acc[2], acc[3]);
    } else {
#pragma unroll
      for (int j = 0; j < VEC; ++j) outf[(size_t)row * N + n + j] = acc[j];
    }
  }
}

// ---------------- max over k, then hh = relu(qenc) * g2max (bf16 out) ----------------
__global__ void reduce_hh_kernel(const float* __restrict__ g2, const float* __restrict__ qenc,
                                 short* __restrict__ hhb) {
  int i = blockIdx.x * blockDim.x + threadIdx.x;
  if (i >= B_ * HID_) return;
  int b = i >> 10, n = i & (HID_ - 1);
  const float* p = g2 + (size_t)b * KOBJ * HID_ + n;
  float mx = -INFINITY;
  for (int k = 0; k < KOBJ; ++k) mx = fmaxf(mx, p[(size_t)k * HID_]);
  hhb[i] = f2bf(fmaxf(qenc[i], 0.f) * mx);
}

extern "C" void kernel_launch(void* const* d_in, const int* in_sizes, int n_in,
                              void* d_out, int out_size, void* d_ws, size_t ws_size,
                              hipStream_t stream) {
  const float* question = (const float*)d_in[0];
  const float* image    = (const float*)d_in[1];
  const float* W_lproj  = (const float*)d_in[3];
  const float* b_lproj  = (const float*)d_in[4];
  const float* W_e1     = (const float*)d_in[5];
  const float* b_e1     = (const float*)d_in[6];
  const float* W_e2     = (const float*)d_in[7];
  const float* b_e2     = (const float*)d_in[8];
  const float* conv_w1  = (const float*)d_in[9];
  const float* mr1 = (const float*)d_in[10];
  const float* mt1 = (const float*)d_in[11];
  const float* pr1 = (const float*)d_in[12];
  const float* pt1 = (const float*)d_in[13];
  const float* conv_w2  = (const float*)d_in[14];
  const float* mr2 = (const float*)d_in[15];
  const float* mt2 = (const float*)d_in[16];
  const float* pr2 = (const float*)d_in[17];
  const float* pt2 = (const float*)d_in[18];
  const float* W_o1 = (const float*)d_in[19];
  const float* b_o1 = (const float*)d_in[20];
  const float* W_o2 = (const float*)d_in[21];
  const float* b_o2 = (const float*)d_in[22];

  float* out = (float*)d_out;
  float* logits = out;               // [32,3000]
  float* adj = out + B_ * OUT_;      // [32,100,100]

  char* ws = (char*)d_ws;
  size_t off = 0;
  auto alloc = [&](size_t bytes) { char* p = ws + off; off += (bytes + 255) & ~((size_t)255); return p; };
  float* qenc  = (float*)alloc((size_t)B_ * HID_ * 4);
  short* qh    = (short*)alloc((size_t)B_ * EMB_ * 2);
  short* ql    = (short*)alloc((size_t)B_ * EMB_ * 2);
  short* qeh   = (short*)alloc((size_t)B_ * HID_ * 2);
  short* qel   = (short*)alloc((size_t)B_ * HID_ * 2);
  short* wlph  = (short*)alloc((size_t)EMB_ * HID_ * 2);
  short* wlpl  = (short*)alloc((size_t)EMB_ * HID_ * 2);
  short* we1ah = (short*)alloc((size_t)COMB_ * KP1 * 2);
  short* we1al = (short*)alloc((size_t)COMB_ * KP1 * 2);
  short* we1bh = (short*)alloc((size_t)COMB_ * HID_ * 2);
  short* we1bl = (short*)alloc((size_t)COMB_ * HID_ * 2);
  short* we2h  = (short*)alloc((size_t)COMB_ * COMB_ * 2);
  short* we2l  = (short*)alloc((size_t)COMB_ * COMB_ * 2);
  float* q1    = (float*)alloc((size_t)B_ * COMB_ * 4);
  short* h1h   = (short*)alloc((size_t)B_ * KOBJ * COMB_ * 2);
  short* h1l   = (short*)alloc((size_t)B_ * KOBJ * COMB_ * 2);
  short* h2h   = (short*)alloc((size_t)(B_ * KOBJ + 128) * COMB_ * 2);  // +pad rows for adj over-read
  short* h2l   = (short*)alloc((size_t)(B_ * KOBJ + 128) * COMB_ * 2);
  float* cent  = (float*)alloc((size_t)B_ * KOBJ * 2 * 4);
  int*   topi  = (int*)alloc((size_t)B_ * KOBJ * NS_ * 4);
  float* c1    = (float*)alloc((size_t)B_ * KOBJ * NS_ * NK_ * 4);
  float* c2    = (float*)alloc((size_t)B_ * KOBJ * NS_ * NK_ * 4);
  short* imgb  = (short*)alloc((size_t)B_ * KOBJ * KP1 * 2);
  short* imgl  = (short*)alloc((size_t)B_ * KOBJ * KP1 * 2);
  short* cw1t  = (short*)alloc((size_t)(2 * HID_) * KP1 * 2);
  short* cw2t  = (short*)alloc((size_t)HID_ * KP2 * 2);
  short* proj1b = (short*)alloc((size_t)B_ * KOBJ * 2 * HID_ * 2);
  short* g1b   = (short*)alloc((size_t)B_ * KOBJ * KP2 * 2);
  short* proj2b = (short*)alloc((size_t)B_ * KOBJ * HID_ * 2);
  float* g2    = (float*)alloc((size_t)B_ * KOBJ * HID_ * 4);
  short* hhb   = (short*)alloc((size_t)B_ * HID_ * 2);
  short* wo1t  = (short*)alloc((size_t)NO_P * HID_ * 2);
  short* wo2t  = (short*)alloc((size_t)NO_P * KO2 * 2);
  short* h1ob  = (short*)alloc((size_t)B_ * KO2 * 2);
  float* partE = (float*)alloc((size_t)4 * B_ * KOBJ * COMB_ * 4);      // f32 partials
  short* partP = (short*)alloc((size_t)4 * B_ * KOBJ * HID_ * 2);       // bf16 partials (proj2)
  (void)ws_size; (void)in_sizes; (void)n_in; (void)out_size;

  dim3 blk(256), blk512(512);

  // ---- ONE dispatch: weight transposes + input cvt + centres ----
  {
    TDs ds;
    int cum = 0;
    auto set = [&](int i, const float* in, short* oh, short* ol, int K, int N, int Kp,
                   int OPM, int nnt, int split, int conv) {
      int nkt = Kp / 64;
      cum += nkt * nnt;
      ds.d[i] = TD{in, oh, ol, K, N, Kp, OPM, nkt, split, conv, cum};
    };
    set(0, W_lproj, wlph, wlpl, EMB_, HID_, EMB_, 0, HID_ / 64, 1, 0);
    set(1, W_e1, we1ah, we1al, FEAT_, COMB_, KP1, 0, COMB_ / 64, 1, 0);
    set(2, W_e1 + (size_t)FEAT_ * COMB_, we1bh, we1bl, HID_, COMB_, HID_, 0, COMB_ / 64, 1, 0);
    set(3, W_e2, we2h, we2l, COMB_, COMB_, COMB_, 0, COMB_ / 64, 1, 0);
    set(4, conv_w1, cw1t, nullptr, FEAT_, 2 * HID_, KP1, 2 * HID_ / NK_, 2 * HID_ / 64, 0, 1);
    set(5, conv_w2, cw2t, nullptr, 2 * HID_, HID_, KP2, HID_ / NK_, HID_ / 64, 0, 1);
    set(6, W_o1, wo1t, nullptr, HID_, OUT_, HID_, 0, NO_P / 64, 0, 0);
    set(7, W_o2, wo2t, nullptr, OUT_, OUT_, KO2, 0, NO_P / 64, 0, 0);
    prep_all<<<dim3(cum + IMG_BLKS + Q_BLKS + C_BLKS), blk, 0, stream>>>(
        ds, cum, image, question, imgb, imgl, qh, ql, cent);
  }

  // ---- FUSED head: e1 (z=4 f32 partials, KS=576) + proj1 (direct bf16) + qenc ----
  fused_head<<<dim3(E1B + P1B + QEB), blk512, 49152, stream>>>(
      imgb, imgl, we1ah, we1al, partE, cw1t, proj1b,
      qh, ql, wlph, wlpl, b_lproj, qenc, qeh, qel);
  // ---- q1 = qenc @ We1[2052:] (split, no bias) ----
  gemm_mx<32, 64, 2, 2, true, false, false, 0, false, false><<<dim3(COMB_ / 64, 1, 1), blk, 0, stream>>>(
      qeh, qel, we1bh, we1bl, nullptr, q1, nullptr, nullptr, nullptr, nullptr, 0, B_, COMB_, HID_, COMB_, COMB_);
  // ---- h1 = relu(sum + q1[bcast] + b_e1), bf16 hi/lo (SK=4) ----
  reduce_split<1, true, true, true, false><<<dim3(B_ * KOBJ * COMB_ / 4 / 256), blk, 0, stream>>>(
      partE, nullptr, 4, (size_t)B_ * KOBJ * COMB_, b_e1, q1, COMB_, nullptr, h1h, h1l,
      B_ * KOBJ, COMB_, COMB_, COMB_);
  // ---- e2: split-K partials f32 (z=4, KS=128) ----
  gemm_mx<128, 64, 4, 2, true, false, false, 0, true, false><<<dim3(COMB_ / 64, B_ * KOBJ / 128, 4), blk512, 0, stream>>>(
      h1h, h1l, we2h, we2l, nullptr, nullptr, nullptr, nullptr, partE, nullptr, 128,
      B_ * KOBJ, COMB_, COMB_, COMB_, COMB_);
  // ---- h2 = relu(sum + b_e2) as bf16 hi/lo ----
  reduce_split<1, true, true, false, false><<<dim3(B_ * KOBJ * COMB_ / 4 / 256), blk, 0, stream>>>(
      partE, nullptr, 4, (size_t)B_ * KOBJ * COMB_, b_e2, nullptr, 0, nullptr, h2h, h2l,
      B_ * KOBJ, COMB_, COMB_, COMB_);
  // ---- adj (Gram MFMA) then topk (separate, wave-parallel) ----
  adj_mfma<<<dim3(B_), blk512, 0, stream>>>(h2h, h2l, adj);
  topk_weights_kernel<<<dim3(B_ * KOBJ / 4), blk, 0, stream>>>(
      adj, cent, mr1, mt1, pr1, pt1, mr2, mt2, pr2, pt2, topi, c1, c2);
  // ---- conv path (proj1b ready from fused head) ----
  combine_kernel<8, true><<<dim3(B_ * KOBJ), blk, 0, stream>>>(
      proj1b, c1, topi, nullptr, g1b, 2 * HID_, 8);
  // ---- proj2: 128x128 2x4 z=4 bf16 partials ----
  gemm_mx<128, 128, 2, 4, false, false, false, 0, true, true><<<dim3(HID_ / 128, B_ * KOBJ / 128, 4), blk512, 0, stream>>>(
      g1b, nullptr, cw2t, nullptr, nullptr, nullptr, nullptr, nullptr, nullptr, partP, 512,
      B_ * KOBJ, HID_, KP2, HID_, HID_);
  reduce_split<2, false, false, false, true><<<dim3(B_ * KOBJ * HID_ / 4 / 256), blk, 0, stream>>>(
      nullptr, partP, 4, (size_t)B_ * KOBJ * HID_, nullptr, nullptr, 0, nullptr, proj2b, nullptr,
      B_ * KOBJ, HID_, HID_, HID_);
  combine_kernel<4, false><<<dim3(B_ * KOBJ), blk, 0, stream>>>(
      proj2b, c2, topi, g2, nullptr, HID_, 7);
  // ---- tail ----
  reduce_hh_kernel<<<dim3((B_ * HID_ + 255) / 256), blk, 0, stream>>>(g2, qenc, hhb);
  // o1: split-K z=8, KS=128 (291.3 us best-config tail)
  gemm_mx<32, 128, 1, 4, false, false, false, 0, true, false><<<dim3(NO_P / 128, 1, 8), blk, 0, stream>>>(
      hhb, nullptr, wo1t, nullptr, nullptr, nullptr, nullptr, nullptr, partE, nullptr, 128,
      B_, OUT_, HID_, KO2, KO2);
  reduce_split<2, true, true, false, false><<<dim3((B_ * KO2 / 4 + 255) / 256), blk, 0, stream>>>(
      partE, nullptr, 8, (size_t)B_ * KO2, b_o1, nullptr, 0, nullptr, h1ob, nullptr,
      B_, OUT_, KO2, KO2);
  // o2: split-K z=8, KS=384
  gemm_mx<32, 128, 1, 4, false, false, false, 0, true, false><<<dim3(NO_P / 128, 1, 8), blk, 0, stream>>>(
      h1ob, nullptr, wo2t, nullptr, nullptr, nullptr, nullptr, nullptr, partE, nullptr, 384,
      B_, OUT_, KO2, KO2, KO2);
  reduce_split<0, false, true, false, false><<<dim3((B_ * KO2 / 4 + 255) / 256), blk, 0, stream>>>(
      partE, nullptr, 8, (size_t)B_ * KO2, b_o2, nullptr, 0, logits, nullptr, nullptr,
      B_, OUT_, KO2, OUT_);
}